// Round 3
// baseline (305.725 us; speedup 1.0000x reference)
//
#include <hip/hip_runtime.h>
#include <cstddef>

// HMM forward-backward posterior. Emission terms are state-independent scalars
// per (b,t); they and the batch dim cancel in the per-t state normalization,
// so gamma[b,t,i] == gamma[t,i]. Only the emission-free recursions
// A_t = A_{t-1} (x) M, B_t = M (x) B_{t+1} (log-matmul) matter.
// Three-level chunking: 4096 = 16*16*16. Squarings give M^16, M^256; level-0
// scan (15 steps, M^256) gives 16 super-boundaries; level-1 (16 chunks, 15
// steps, M^16) gives 256 boundaries; level-2 is FUSED with gamma+broadcast:
// 256 blocks each run alpha+beta 15-step chains in LDS, normalize, and stream
// 64 contiguous 8KB segments to out (134 MB total, the HBM write floor).
// Per-step renorm uses x[0] as reference (any per-t constant cancels at the
// final per-t normalization).

constexpr int NS = 128;
constexpr int TT = 4096;
constexpr int NB = 64;
constexpr int LVL = 16;   // chunk length at every level

// workspace offsets (floats)
constexpr int OFF_P0   = 0;
constexpr int OFF_P1   = 16384;
constexpr int OFF_P16  = 32768;   // M^16 (log)
constexpr int OFF_P256 = 49152;   // M^256 (log)
constexpr int OFF_EBASE = 65536;  // 3 mats x {EA 16384, EB 16384, CM 128, RM 128}
constexpr int EMAT_STRIDE = 33024;
constexpr int OFF_AB1 = 164608;   // 16  x128 alpha boundaries (t=256c)
constexpr int OFF_BB1 = 166656;   // 16  x128 beta  boundaries (t=256c+255)
constexpr int OFF_AB2 = 168704;   // 256 x128 alpha boundaries (t=16d)
constexpr int OFF_BB2 = 201472;   // 256 x128 beta  boundaries (t=16d+15)
// total 234,240 floats ~ 0.9 MiB

__device__ __forceinline__ float wredmax(float v) {
#pragma unroll
  for (int off = 32; off; off >>= 1) v = fmaxf(v, __shfl_xor(v, off, 64));
  return v;
}
__device__ __forceinline__ float wredsum(float v) {
#pragma unroll
  for (int off = 32; off; off >>= 1) v += __shfl_xor(v, off, 64);
  return v;
}

// Log-matmul squaring P = A (x) A. One block per output row; lane i holds
// exp(A[:,i]-colmax_i) in 128 VGPRs; row weights broadcast via LDS.
__global__ __launch_bounds__(128, 1) void sq_log(const float* __restrict__ A,
                                                 float* __restrict__ P) {
  __shared__ float wsm[NS];
  __shared__ float red[2];
  int i = threadIdx.x;
  int row = blockIdx.x;
  float Ereg[NS];
  float c = -1e30f;
#pragma unroll
  for (int j = 0; j < NS; ++j) { float v = A[j * NS + i]; Ereg[j] = v; c = fmaxf(c, v); }
#pragma unroll
  for (int j = 0; j < NS; ++j) Ereg[j] = __expf(Ereg[j] - c);
  float xr = A[row * NS + i];
  float m = wredmax(xr);
  if ((i & 63) == 0) red[i >> 6] = m;
  __syncthreads();
  float rm = fmaxf(red[0], red[1]);
  wsm[i] = __expf(xr - rm);
  __syncthreads();
  float acc = 0.f;
  const float4* w4 = (const float4*)wsm;
#pragma unroll
  for (int j = 0; j < 32; ++j) {
    float4 wv = w4[j];
    acc += wv.x * Ereg[4 * j] + wv.y * Ereg[4 * j + 1] +
           wv.z * Ereg[4 * j + 2] + wv.w * Ereg[4 * j + 3];
  }
  P[row * NS + i] = __logf(fmaxf(acc, 1e-37f)) + rm + c;
}

// Both rescaled exp layouts of a 128x128 log matrix in ONE launch.
// block 0: column-rescaled EA[j*128+i]=exp(src[j][i]-colmax_i) (coalesced).
// blocks 1..16: 8 rows each -> EB[k*128+i]=exp(src[i][k]-rowmax_i)
// (coalesced reads, scattered fire-and-forget stores).
__global__ void prep_mat(const float* __restrict__ src, float* __restrict__ ws, int m) {
  float* Ea = ws + OFF_EBASE + m * EMAT_STRIDE;
  float* Eb = Ea + 16384;
  float* cm = Ea + 32768;
  float* rm = Ea + 32896;
  if (blockIdx.x == 0) {
    int i = threadIdx.x;
    float mx = -1e30f;
    for (int j = 0; j < NS; ++j) mx = fmaxf(mx, src[j * NS + i]);
    cm[i] = mx;
    for (int j = 0; j < NS; ++j) Ea[j * NS + i] = __expf(src[j * NS + i] - mx);
  } else {
    int blk = blockIdx.x - 1;  // 0..15
    int k = threadIdx.x;
    __shared__ float red[2];
    for (int r = 0; r < 8; ++r) {
      int i = blk * 8 + r;
      float v = src[i * NS + k];
      float mx = wredmax(v);
      if ((k & 63) == 0) red[k >> 6] = mx;
      __syncthreads();
      mx = fmaxf(red[0], red[1]);
      Eb[k * NS + i] = __expf(v - mx);
      if (k == 0) rm[i] = mx;
      __syncthreads();
    }
  }
}

// Boundary scan level: grid = 2*numChunks (alpha blocks then beta blocks).
// Each block: E column in regs, 15 steps, store all 16 vectors.
__global__ __launch_bounds__(128, 1) void scan_level(
    const float* __restrict__ EaP, const float* __restrict__ cmP,
    const float* __restrict__ EbP, const float* __restrict__ rmP,
    const float* __restrict__ inA, const float* __restrict__ inB,
    float* __restrict__ outA, float* __restrict__ outB, int numChunks) {
  __shared__ float xs[NS];
  __shared__ float wsm[NS];
  int lane = threadIdx.x;
  bool isA = (int)blockIdx.x < numChunks;
  int c = isA ? blockIdx.x : blockIdx.x - numChunks;
  const float* E = isA ? EaP : EbP;
  float cm = (isA ? cmP : rmP)[lane];
  float Ereg[NS];
#pragma unroll
  for (int j = 0; j < NS; ++j) Ereg[j] = E[j * NS + lane];
  float x = isA ? inA[c * NS + lane] : (inB ? inB[c * NS + lane] : 0.f);
  float* out = (isA ? outA : outB) + (size_t)c * LVL * NS;
  out[(isA ? 0 : LVL - 1) * NS + lane] = x;
  for (int it = 1; it < LVL; ++it) {
    int scur = isA ? it : LVL - 1 - it;
    xs[lane] = x;
    __syncthreads();
    float ref = xs[0];
    wsm[lane] = __expf(x - ref);
    __syncthreads();
    float acc = 0.f;
    const float4* w4 = (const float4*)wsm;
#pragma unroll
    for (int j = 0; j < 32; ++j) {
      float4 wv = w4[j];
      acc += wv.x * Ereg[4 * j] + wv.y * Ereg[4 * j + 1] +
             wv.z * Ereg[4 * j + 2] + wv.w * Ereg[4 * j + 3];
    }
    x = __logf(fmaxf(acc, 1e-37f)) + cm;
    out[scur * NS + lane] = x;
  }
}

// FUSED level-2 + gamma + broadcast. 256 blocks (one per 16-t chunk), 256
// threads: tid<128 alpha chain, tid>=128 beta chain, lockstep barriers.
// Chains land in LDS Ga/Gb; per-t normalize; stream 64 contiguous 8KB
// segments per block to out.
__global__ __launch_bounds__(256, 1) void scan_gamma(const float* __restrict__ ws,
                                                     float* __restrict__ out) {
  __shared__ __align__(16) float Ga[LVL][NS];
  __shared__ __align__(16) float Gb[LVL][NS];
  __shared__ float wsA[NS];
  __shared__ float wsB[NS];
  int tid = threadIdx.x;
  int c = blockIdx.x;
  bool isA = tid < NS;
  int lane = tid & (NS - 1);
  const float* Ea = ws + OFF_EBASE;         // matrix m=0 (M itself)
  const float* Eb = Ea + 16384;
  const float* cmv = Ea + 32768;
  const float* rmv = Ea + 32896;
  const float* E = isA ? Ea : Eb;
  float cm = (isA ? cmv : rmv)[lane];
  float Ereg[NS];
#pragma unroll
  for (int j = 0; j < NS; ++j) Ereg[j] = E[j * NS + lane];
  float x;
  if (isA) {
    x = ws[OFF_AB2 + c * NS + lane];
    Ga[0][lane] = x;
  } else {
    x = ws[OFF_BB2 + c * NS + lane];
    Gb[LVL - 1][lane] = x;
  }
  float* wbuf = isA ? wsA : wsB;
  __syncthreads();
  for (int it = 1; it < LVL; ++it) {
    int sprev = isA ? it - 1 : LVL - it;
    int scur = isA ? it : LVL - 1 - it;
    float ref = isA ? Ga[sprev][0] : Gb[sprev][0];
    wbuf[lane] = __expf(x - ref);
    __syncthreads();
    float acc = 0.f;
    const float4* w4 = (const float4*)wbuf;
#pragma unroll
    for (int j = 0; j < 32; ++j) {
      float4 wv = w4[j];
      acc += wv.x * Ereg[4 * j] + wv.y * Ereg[4 * j + 1] +
             wv.z * Ereg[4 * j + 2] + wv.w * Ereg[4 * j + 3];
    }
    x = __logf(fmaxf(acc, 1e-37f)) + cm;
    if (isA) Ga[scur][lane] = x; else Gb[scur][lane] = x;
    __syncthreads();
  }
  // gamma: wave w normalizes rows 4w..4w+3 (lane l covers i=l and i=l+64)
  int w = tid >> 6;
  int l = tid & 63;
#pragma unroll
  for (int r = 0; r < 4; ++r) {
    int s = w * 4 + r;
    float a0 = Ga[s][l] + Gb[s][l];
    float a1 = Ga[s][l + 64] + Gb[s][l + 64];
    float mx = wredmax(fmaxf(a0, a1));
    float p = __expf(a0 - mx) + __expf(a1 - mx);
    float sm = wredsum(p);
    float lse = __logf(sm) + mx;
    Ga[s][l] = a0 - lse;
    Ga[s][l + 64] = a1 - lse;
  }
  __syncthreads();
  // broadcast: 64 batches x contiguous 8KB (16 t x 128 states) per block
  const float4* G4 = (const float4*)Ga;
  float4 v0 = G4[tid];
  float4 v1 = G4[tid + 256];
  float4* o4 = (float4*)out;
  for (int b = 0; b < NB; ++b) {
    float4* dst = o4 + ((size_t)b * TT + (size_t)c * LVL) * (NS / 4);
    dst[tid] = v0;
    dst[tid + 256] = v1;
  }
}

extern "C" void kernel_launch(void* const* d_in, const int* in_sizes, int n_in,
                              void* d_out, int out_size, void* d_ws, size_t ws_size,
                              hipStream_t stream) {
  (void)in_sizes; (void)n_in; (void)out_size; (void)ws_size;
  const float* pi = (const float*)d_in[1];
  const float* Tm = (const float*)d_in[2];
  float* ws = (float*)d_ws;
  float* out = (float*)d_out;

  float* P0 = ws + OFF_P0;
  float* P1 = ws + OFF_P1;
  float* P16 = ws + OFF_P16;
  float* P256 = ws + OFF_P256;

  prep_mat<<<17, 128, 0, stream>>>(Tm, ws, 0);
  sq_log<<<128, 128, 0, stream>>>(Tm, P0);     // M^2
  sq_log<<<128, 128, 0, stream>>>(P0, P1);     // M^4
  sq_log<<<128, 128, 0, stream>>>(P1, P0);     // M^8
  sq_log<<<128, 128, 0, stream>>>(P0, P16);    // M^16
  prep_mat<<<17, 128, 0, stream>>>(P16, ws, 1);
  sq_log<<<128, 128, 0, stream>>>(P16, P0);    // M^32
  sq_log<<<128, 128, 0, stream>>>(P0, P1);     // M^64
  sq_log<<<128, 128, 0, stream>>>(P1, P0);     // M^128
  sq_log<<<128, 128, 0, stream>>>(P0, P256);   // M^256
  prep_mat<<<17, 128, 0, stream>>>(P256, ws, 2);

  auto EA = [&](int m) { return ws + OFF_EBASE + m * EMAT_STRIDE; };
  auto EB = [&](int m) { return EA(m) + 16384; };
  auto CM = [&](int m) { return EA(m) + 32768; };
  auto RM = [&](int m) { return EA(m) + 32896; };

  // level 0: 1 chunk, M^256 -> 16 super-boundaries each direction
  scan_level<<<2, 128, 0, stream>>>(EA(2), CM(2), EB(2), RM(2),
                                    pi, nullptr, ws + OFF_AB1, ws + OFF_BB1, 1);
  // level 1: 16 chunks, M^16 -> 256 boundaries
  scan_level<<<32, 128, 0, stream>>>(EA(1), CM(1), EB(1), RM(1),
                                     ws + OFF_AB1, ws + OFF_BB1,
                                     ws + OFF_AB2, ws + OFF_BB2, 16);
  // level 2 fused with gamma + broadcast write
  scan_gamma<<<256, 256, 0, stream>>>(ws, out);
}